// Round 4
// baseline (204.083 us; speedup 1.0000x reference)
//
#include <hip/hip_runtime.h>

#define R_    116
#define RP    128
#define DIN_  116
#define H_    256

typedef float  f32x4  __attribute__((ext_vector_type(4)));
typedef short  short8 __attribute__((ext_vector_type(8)));
typedef int    int4v  __attribute__((ext_vector_type(4)));

// ---- LDS layout (bytes). All matrices XOR-swizzled: 16B-block index ^= (row&7).
#define AT_OFF   0        // At [128 c][128 r] bf16, pitch 256B : At[c][r]=max(m[r][c],0)+(r==c)
#define X_OFF    32768    // X  [128 r][128 k] bf16, pitch 256B : node features, zero-padded
#define H1_OFF   65536    // H1 [128 c][256 f] bf16, pitch 512B
#define DINV_OFF 131072   // 128 f32
#define RED_OFF  131584   // 16 f32
#define LDS_SIZE 131648

__device__ __forceinline__ short f2bf(float f) {
  union { float f; unsigned u; } x; x.f = f;
  unsigned r = x.u + 0x7fffu + ((x.u >> 16) & 1u);
  return (short)(r >> 16);
}
__device__ __forceinline__ float bf2f(short s) {
  union { unsigned u; float f; } x;
  x.u = ((unsigned)(unsigned short)s) << 16;
  return x.f;
}
__device__ __forceinline__ unsigned pack2(float lo, float hi) {
  return (unsigned)(unsigned short)f2bf(lo) | ((unsigned)(unsigned short)f2bf(hi) << 16);
}

union U8 { short8 s; unsigned u[4]; };

// Pre-transpose weights to bf16 Wt[f][k], zero-padded K (layer 1).
__global__ void __launch_bounds__(256) wt_setup(const float* __restrict__ W1,
                                                const float* __restrict__ W2,
                                                short* __restrict__ W1t,
                                                short* __restrict__ W2t) {
  int idx = blockIdx.x * 256 + threadIdx.x;      // 384 blocks
  if (idx < 32768) {                             // W1t [256][128]
    int f = idx >> 7, k = idx & 127;
    float v = (k < DIN_) ? W1[k * H_ + f] : 0.f;
    W1t[idx] = f2bf(v);
  } else {                                       // W2t [256][256]
    int j = idx - 32768;
    int f = j >> 8, k = j & 255;
    W2t[j] = f2bf(W2[k * H_ + f]);
  }
}

// In-register xs -> agg, textually inlined (NO pointers to local arrays:
// pointer-passing forced acc/dvr/acc2 into scratch -> 267MB spill traffic in r2/r3).
// ACCV holds xw (C/D layout: col=i16, row=q*4+e per 16-tile).
// ACC2V += At @ (dinv*xw) over k=0..127 via intra-wave shuffle B-frags.
#define AGG_FROM_ACC(ACCV, ACC2V)                                               \
  do {                                                                          \
    unsigned P0[8], P1[8];                                                      \
    _Pragma("unroll") for (int mt = 0; mt < 8; ++mt) {                          \
      P0[mt] = pack2(ACCV[mt][0] * dvr[mt][0], ACCV[mt][1] * dvr[mt][1]);       \
      P1[mt] = pack2(ACCV[mt][2] * dvr[mt][2], ACCV[mt][3] * dvr[mt][3]);       \
    }                                                                           \
    _Pragma("unroll") for (int ks = 0; ks < 4; ++ks) {                          \
      unsigned a0 = (unsigned)__shfl((int)P0[2 * ks], srcA);                    \
      unsigned b0 = (unsigned)__shfl((int)P0[2 * ks + 1], srcA);                \
      unsigned a1 = (unsigned)__shfl((int)P1[2 * ks], srcA);                    \
      unsigned b1 = (unsigned)__shfl((int)P1[2 * ks + 1], srcA);                \
      unsigned a2 = (unsigned)__shfl((int)P0[2 * ks], srcB);                    \
      unsigned b2 = (unsigned)__shfl((int)P0[2 * ks + 1], srcB);                \
      unsigned a3 = (unsigned)__shfl((int)P1[2 * ks], srcB);                    \
      unsigned b3 = (unsigned)__shfl((int)P1[2 * ks + 1], srcB);                \
      U8 bfu;                                                                   \
      bfu.u[0] = hi ? b0 : a0;                                                  \
      bfu.u[1] = hi ? b1 : a1;                                                  \
      bfu.u[2] = hi ? b2 : a2;                                                  \
      bfu.u[3] = hi ? b3 : a3;                                                  \
      _Pragma("unroll") for (int ct = 0; ct < 8; ++ct) {                        \
        int bb = (ks * 4 + q) ^ (i16 & 7);                                      \
        short8 atf = *(const short8*)(smem + AT_OFF +                           \
                                      (ct * 16 + i16) * 256 + bb * 16);         \
        ACC2V[ct] = __builtin_amdgcn_mfma_f32_16x16x32_bf16(atf, bfu.s,         \
                                                            ACC2V[ct], 0, 0, 0);\
      }                                                                         \
    }                                                                           \
  } while (0)

__global__ void __launch_bounds__(512, 2) gnn_fused(
    const float* __restrict__ mM, const float* __restrict__ nf,
    const float* __restrict__ b1, const float* __restrict__ b2,
    const float* __restrict__ Wc, const float* __restrict__ bc,
    const short* __restrict__ W1t, const short* __restrict__ W2t,
    float* __restrict__ out)
{
  extern __shared__ char smem[];
  const int b    = blockIdx.x;
  const int tid  = threadIdx.x;
  const int lane = tid & 63;
  const int w    = tid >> 6;     // 0..7 : which 16-col f group
  const int i16  = lane & 15;
  const int q    = lane >> 4;
  const int srcA = i16 + 32 * (q & 1);
  const int srcB = srcA + 16;
  const bool hi  = q >= 2;

  float* dinvp = (float*)(smem + DINV_OFF);

  // ---- zero At + X (covers padding rows/cols) ----
  for (int t = tid; t < 65536 / 16; t += 512)
    ((int4v*)(smem + AT_OFF))[t] = (int4v){0, 0, 0, 0};
  __syncthreads();

  // ---- fill At (transposed, relu, +1 diag) and X (bf16), coalesced f32x4 reads ----
  {
    const float* mB = mM + (size_t)b * (R_ * R_);
    const float* xB = nf + (size_t)b * (R_ * DIN_);   // contiguous batch slice
    for (int t4 = tid; t4 < (R_ * R_) / 4; t4 += 512) {
      f32x4 v4 = ((const f32x4*)mB)[t4];
      f32x4 x4 = ((const f32x4*)xB)[t4];
#pragma unroll
      for (int e = 0; e < 4; ++e) {
        int i = t4 * 4 + e;
        int r = i / R_, c = i - r * R_;
        float v = v4[e];
        v = v > 0.f ? v : 0.f;
        if (r == c) v += 1.f;
        int ba = (r >> 3) ^ (c & 7);
        *(short*)(smem + AT_OFF + c * 256 + ba * 16 + (r & 7) * 2) = f2bf(v);
        int bx = (c >> 3) ^ (r & 7);
        *(short*)(smem + X_OFF + r * 256 + bx * 16 + (c & 7) * 2) = f2bf(x4[e]);
      }
    }
  }
  __syncthreads();

  // ---- deg/dinv: 4 threads per row ----
  {
    int row = tid >> 2, part = tid & 3;
    float s = 0.f;
#pragma unroll
    for (int j = 0; j < 4; ++j) {
      int bb = (part * 4 + j) ^ (row & 7);
      short8 v = *(const short8*)(smem + AT_OFF + row * 256 + bb * 16);
#pragma unroll
      for (int e = 0; e < 8; ++e) s += bf2f(v[e]);
    }
    s += __shfl_xor(s, 1);
    s += __shfl_xor(s, 2);
    if ((tid & 3) == 0) dinvp[row] = (row < R_) ? rsqrtf(s) : 0.f;
  }
  __syncthreads();

  f32x4 dvr[8];
#pragma unroll
  for (int mt = 0; mt < 8; ++mt) dvr[mt] = *(const f32x4*)(dinvp + mt * 16 + q * 4);

  const int fbl = w * 16 + i16;

  // ================= Layer 1 =================
#pragma unroll 1
  for (int pass = 0; pass < 2; ++pass) {
    const int f = pass * 128 + fbl;
    f32x4 acc[8];
#pragma unroll
    for (int mt = 0; mt < 8; ++mt) acc[mt] = (f32x4){0.f, 0.f, 0.f, 0.f};

#pragma unroll
    for (int ks = 0; ks < 4; ++ks) {
      short8 wf = *(const short8*)(W1t + (size_t)f * 128 + ks * 32 + q * 8);
#pragma unroll
      for (int mt = 0; mt < 8; ++mt) {
        int bb = (ks * 4 + q) ^ (i16 & 7);
        short8 af = *(const short8*)(smem + X_OFF + (mt * 16 + i16) * 256 + bb * 16);
        acc[mt] = __builtin_amdgcn_mfma_f32_16x16x32_bf16(af, wf, acc[mt], 0, 0, 0);
      }
    }

    f32x4 acc2[8];
#pragma unroll
    for (int ct = 0; ct < 8; ++ct) acc2[ct] = (f32x4){0.f, 0.f, 0.f, 0.f};
    AGG_FROM_ACC(acc, acc2);

    float bias = b1[f];
    const int fB = f >> 3, f7 = (f & 7) * 2;
#pragma unroll
    for (int ct = 0; ct < 8; ++ct) {
#pragma unroll
      for (int e = 0; e < 4; ++e) {
        int c = ct * 16 + q * 4 + e;
        float h = dvr[ct][e] * acc2[ct][e] + bias;
        h = h > 0.f ? h : 0.2f * h;
        int bb = fB ^ (c & 7);
        *(short*)(smem + H1_OFF + c * 512 + bb * 16 + f7) = f2bf(h);
      }
    }
  }
  __syncthreads();   // H1 complete

  // ================= Layer 2 =================
  float ps0 = 0.f, ps1 = 0.f;
#pragma unroll 1
  for (int pass = 0; pass < 2; ++pass) {
    const int f = pass * 128 + fbl;
    f32x4 acc[8];
#pragma unroll
    for (int mt = 0; mt < 8; ++mt) acc[mt] = (f32x4){0.f, 0.f, 0.f, 0.f};

#pragma unroll
    for (int ks = 0; ks < 8; ++ks) {
      short8 wf = *(const short8*)(W2t + (size_t)f * 256 + ks * 32 + q * 8);
#pragma unroll
      for (int mt = 0; mt < 8; ++mt) {
        int bb = (ks * 4 + q) ^ (i16 & 7);
        short8 af = *(const short8*)(smem + H1_OFF + (mt * 16 + i16) * 512 + bb * 16);
        acc[mt] = __builtin_amdgcn_mfma_f32_16x16x32_bf16(af, wf, acc[mt], 0, 0, 0);
      }
    }

    f32x4 acc2[8];
#pragma unroll
    for (int ct = 0; ct < 8; ++ct) acc2[ct] = (f32x4){0.f, 0.f, 0.f, 0.f};
    AGG_FROM_ACC(acc, acc2);

    float bias = b2[f];
#pragma unroll
    for (int ct = 0; ct < 8; ++ct) {
#pragma unroll
      for (int e = 0; e < 4; ++e) {
        int c = ct * 16 + q * 4 + e;
        if (c < R_) {
          float h = dvr[ct][e] * acc2[ct][e] + bias;
          h = h > 0.f ? h : 0.2f * h;
          size_t j = (size_t)c * H_ + f;
          ps0 += h * Wc[j];
          ps1 += h * Wc[(size_t)(H_ * R_) + j];
        }
      }
    }
  }

  // ---- classifier reduction ----
#pragma unroll
  for (int off = 32; off; off >>= 1) {
    ps0 += __shfl_xor(ps0, off, 64);
    ps1 += __shfl_xor(ps1, off, 64);
  }
  float* red = (float*)(smem + RED_OFF);
  if (lane == 0) { red[w * 2] = ps0; red[w * 2 + 1] = ps1; }
  __syncthreads();
  if (tid == 0) {
    float s0 = 0.f, s1 = 0.f;
    for (int i = 0; i < 8; ++i) { s0 += red[i * 2]; s1 += red[i * 2 + 1]; }
    out[b * 2 + 0] = s0 + bc[0];
    out[b * 2 + 1] = s1 + bc[1];
  }
}

extern "C" void kernel_launch(void* const* d_in, const int* in_sizes, int n_in,
                              void* d_out, int out_size, void* d_ws, size_t ws_size,
                              hipStream_t stream) {
  const float* mM = (const float*)d_in[0];
  const float* nf = (const float*)d_in[1];
  const float* W1 = (const float*)d_in[2];
  const float* b1 = (const float*)d_in[3];
  const float* W2 = (const float*)d_in[4];
  const float* b2 = (const float*)d_in[5];
  const float* Wc = (const float*)d_in[6];
  const float* bc = (const float*)d_in[7];
  float* out = (float*)d_out;

  short* W1t = (short*)d_ws;            // 32768 bf16
  short* W2t = W1t + 32768;             // 65536 bf16

  wt_setup<<<384, 256, 0, stream>>>(W1, W2, W1t, W2t);

  hipFuncSetAttribute((const void*)gnn_fused,
                      hipFuncAttributeMaxDynamicSharedMemorySize, LDS_SIZE);
  gnn_fused<<<512, 512, LDS_SIZE, stream>>>(mM, nf, b1, b2, Wc, bc, W1t, W2t, out);
}

// Round 5
// 67.757 us; speedup vs baseline: 3.0120x; 3.0120x over previous
//
#include <hip/hip_runtime.h>

#define R_    116
#define DIN_  116
#define H_    256

typedef float  f32x4  __attribute__((ext_vector_type(4)));
typedef short  short8 __attribute__((ext_vector_type(8)));
typedef int    int4v  __attribute__((ext_vector_type(4)));
typedef int    int2v  __attribute__((ext_vector_type(2)));

// ---- LDS layout (bytes), total exactly 160 KiB. 16B-block XOR swizzle per row.
#define AT_OFF   0        // At [128 c][128 r] bf16 pitch 256B : bb=(r>>3)^(c&7); At[c][r]=max(m[r][c],0)+(r==c)
#define X_OFF    32768    // X  [128 r][128 k] bf16 pitch 256B : bb=(k>>3)^(r&7); zero-padded
#define XS_OFF   65536    // XS [128 f][128 r] bf16 pitch 256B : bb=(r>>3)^(f&7); also temp dinv / final red
#define H1_OFF   98304    // H1 [128 r][256 f] bf16 pitch 512B : bb=(f>>3)^(r&7)
#define LDS_SIZE 163840

__device__ __forceinline__ short f2bf(float f) {
  union { float f; unsigned u; } x; x.f = f;
  unsigned r = x.u + 0x7fffu + ((x.u >> 16) & 1u);
  return (short)(r >> 16);
}
__device__ __forceinline__ float bf2f(short s) {
  union { unsigned u; float f; } x;
  x.u = ((unsigned)(unsigned short)s) << 16;
  return x.f;
}
__device__ __forceinline__ unsigned pack2(float lo, float hi) {
  return (unsigned)(unsigned short)f2bf(lo) | ((unsigned)(unsigned short)f2bf(hi) << 16);
}

// Pre-transpose weights to bf16 Wt[f][k], zero-padded K (layer 1).
__global__ void __launch_bounds__(256) wt_setup(const float* __restrict__ W1,
                                                const float* __restrict__ W2,
                                                short* __restrict__ W1t,
                                                short* __restrict__ W2t) {
  int idx = blockIdx.x * 256 + threadIdx.x;      // 384 blocks
  if (idx < 32768) {                             // W1t [256][128]
    int f = idx >> 7, k = idx & 127;
    float v = (k < DIN_) ? W1[k * H_ + f] : 0.f;
    W1t[idx] = f2bf(v);
  } else {                                       // W2t [256][256]
    int j = idx - 32768;
    int f = j >> 8, k = j & 255;
    W2t[j] = f2bf(W2[k * H_ + f]);
  }
}

__global__ void __launch_bounds__(512, 2) gnn_fused(
    const float* __restrict__ mM, const float* __restrict__ nf,
    const float* __restrict__ b1, const float* __restrict__ b2,
    const float* __restrict__ Wc, const float* __restrict__ bc,
    const short* __restrict__ W1t, const short* __restrict__ W2t,
    float* __restrict__ out)
{
  extern __shared__ char smem[];
  const int b    = blockIdx.x;
  const int tid  = threadIdx.x;
  const int lane = tid & 63;
  const int w    = tid >> 6;     // 0..7 : which 16-col f group
  const int i16  = lane & 15;
  const int q    = lane >> 4;

  // ---- zero At + X (64KB; covers all padding) ----
  for (int t = tid; t < 65536 / 16; t += 512)
    ((int4v*)smem)[t] = (int4v){0, 0, 0, 0};
  __syncthreads();

  // ---- fill At (transposed, relu, +1 diag) and X (bf16), coalesced f32x4 reads ----
  {
    const float* mB = mM + (size_t)b * (R_ * R_);
    const float* xB = nf + (size_t)b * (R_ * DIN_);
    for (int t4 = tid; t4 < (R_ * R_) / 4; t4 += 512) {
      f32x4 v4 = ((const f32x4*)mB)[t4];
      f32x4 x4 = ((const f32x4*)xB)[t4];
#pragma unroll
      for (int e = 0; e < 4; ++e) {
        int i = t4 * 4 + e;
        int r = i / R_, c = i - r * R_;
        float v = v4[e];
        v = v > 0.f ? v : 0.f;
        if (r == c) v += 1.f;
        int ba = (r >> 3) ^ (c & 7);
        *(short*)(smem + AT_OFF + c * 256 + ba * 16 + (r & 7) * 2) = f2bf(v);
        int bx = (c >> 3) ^ (r & 7);
        *(short*)(smem + X_OFF + r * 256 + bx * 16 + (c & 7) * 2) = f2bf(x4[e]);
      }
    }
  }
  __syncthreads();

  // ---- deg/dinv: 4 threads per row -> temp buffer in the (not-yet-used) XS slot ----
  {
    float* dinvp = (float*)(smem + XS_OFF);
    int row = tid >> 2, part = tid & 3;
    float s = 0.f;
#pragma unroll
    for (int j = 0; j < 4; ++j) {
      int bb = (part * 4 + j) ^ (row & 7);
      short8 v = *(const short8*)(smem + AT_OFF + row * 256 + bb * 16);
#pragma unroll
      for (int e = 0; e < 8; ++e) s += bf2f(v[e]);
    }
    s += __shfl_xor(s, 1);
    s += __shfl_xor(s, 2);
    if (part == 0) dinvp[row] = (row < R_) ? rsqrtf(s) : 0.f;
  }
  __syncthreads();

  // dinv register-resident for both row-frag scaling and col epilogues (identical index map)
  f32x4 dvr[8];
#pragma unroll
  for (int t = 0; t < 8; ++t)
    dvr[t] = *(const f32x4*)((const float*)(smem + XS_OFF) + t * 16 + q * 4);
  __syncthreads();   // all dinv reads done before XS gets overwritten

  const int fb = w * 16 + i16;
  float ps0 = 0.f, ps1 = 0.f;

  // ================= Layer 1 =================
#pragma unroll 1
  for (int hf = 0; hf < 2; ++hf) {
    const int f = hf * 128 + fb;
    // ---- phase A: xw = X @ W1 for this wave's 16 f-cols, all 128 rows ----
    f32x4 acc[8];
#pragma unroll
    for (int mt = 0; mt < 8; ++mt) acc[mt] = (f32x4){0.f, 0.f, 0.f, 0.f};
#pragma unroll
    for (int ks = 0; ks < 4; ++ks) {
      short8 wf = *(const short8*)(W1t + (size_t)f * 128 + ks * 32 + q * 8);
#pragma unroll
      for (int mt = 0; mt < 8; ++mt) {
        int bb = (ks * 4 + q) ^ (i16 & 7);
        short8 af = *(const short8*)(smem + X_OFF + (mt * 16 + i16) * 256 + bb * 16);
        acc[mt] = __builtin_amdgcn_mfma_f32_16x16x32_bf16(af, wf, acc[mt], 0, 0, 0);
      }
    }
    // scale by dinv[r], write xs -> XS[f][r] (8B packed stores)
#pragma unroll
    for (int mt = 0; mt < 8; ++mt) {
      int r0 = mt * 16 + q * 4;
      int2v pk;
      pk[0] = (int)pack2(acc[mt][0] * dvr[mt][0], acc[mt][1] * dvr[mt][1]);
      pk[1] = (int)pack2(acc[mt][2] * dvr[mt][2], acc[mt][3] * dvr[mt][3]);
      int bb = (r0 >> 3) ^ (i16 & 7);          // f&7 == i16&7
      *(int2v*)(smem + XS_OFF + fb * 256 + bb * 16 + (r0 & 7) * 2) = pk;
    }
    __syncthreads();

    // ---- phase B: agg = At @ xs ----
    f32x4 acc2[8];
#pragma unroll
    for (int ct = 0; ct < 8; ++ct) acc2[ct] = (f32x4){0.f, 0.f, 0.f, 0.f};
#pragma unroll
    for (int ks = 0; ks < 4; ++ks) {
      int bb = (ks * 4 + q) ^ (i16 & 7);
      short8 bx = *(const short8*)(smem + XS_OFF + fb * 256 + bb * 16);
#pragma unroll
      for (int ct = 0; ct < 8; ++ct) {
        short8 atf = *(const short8*)(smem + AT_OFF + (ct * 16 + i16) * 256 + bb * 16);
        acc2[ct] = __builtin_amdgcn_mfma_f32_16x16x32_bf16(atf, bx, acc2[ct], 0, 0, 0);
      }
    }
    // epilogue: h1 = leaky(dinv[c]*agg + b1) -> H1[c][f]
    {
      float bias = b1[f];
#pragma unroll
      for (int ct = 0; ct < 8; ++ct) {
#pragma unroll
        for (int e = 0; e < 4; ++e) {
          int c = ct * 16 + q * 4 + e;
          float h = dvr[ct][e] * acc2[ct][e] + bias;
          h = h > 0.f ? h : 0.2f * h;
          int bb = (f >> 3) ^ (c & 7);
          *(short*)(smem + H1_OFF + c * 512 + bb * 16 + (f & 7) * 2) = f2bf(h);
        }
      }
    }
    __syncthreads();   // XS consumed + H1 half written
  }

  // ================= Layer 2 =================
#pragma unroll 1
  for (int hf = 0; hf < 2; ++hf) {
    const int f = hf * 128 + fb;
    // ---- phase A: xw2 = H1 @ W2 (K=256) ----
    f32x4 acc[8];
#pragma unroll
    for (int mt = 0; mt < 8; ++mt) acc[mt] = (f32x4){0.f, 0.f, 0.f, 0.f};
#pragma unroll
    for (int ks = 0; ks < 8; ++ks) {
      short8 wf = *(const short8*)(W2t + (size_t)f * 256 + ks * 32 + q * 8);
#pragma unroll
      for (int mt = 0; mt < 8; ++mt) {
        int bb = (ks * 4 + q) ^ (i16 & 7);
        short8 af = *(const short8*)(smem + H1_OFF + (mt * 16 + i16) * 512 + bb * 16);
        acc[mt] = __builtin_amdgcn_mfma_f32_16x16x32_bf16(af, wf, acc[mt], 0, 0, 0);
      }
    }
#pragma unroll
    for (int mt = 0; mt < 8; ++mt) {
      int r0 = mt * 16 + q * 4;
      int2v pk;
      pk[0] = (int)pack2(acc[mt][0] * dvr[mt][0], acc[mt][1] * dvr[mt][1]);
      pk[1] = (int)pack2(acc[mt][2] * dvr[mt][2], acc[mt][3] * dvr[mt][3]);
      int bb = (r0 >> 3) ^ (i16 & 7);
      *(int2v*)(smem + XS_OFF + fb * 256 + bb * 16 + (r0 & 7) * 2) = pk;
    }
    __syncthreads();

    // ---- phase B: agg ----
    f32x4 acc2[8];
#pragma unroll
    for (int ct = 0; ct < 8; ++ct) acc2[ct] = (f32x4){0.f, 0.f, 0.f, 0.f};
#pragma unroll
    for (int ks = 0; ks < 4; ++ks) {
      int bb = (ks * 4 + q) ^ (i16 & 7);
      short8 bx = *(const short8*)(smem + XS_OFF + fb * 256 + bb * 16);
#pragma unroll
      for (int ct = 0; ct < 8; ++ct) {
        short8 atf = *(const short8*)(smem + AT_OFF + (ct * 16 + i16) * 256 + bb * 16);
        acc2[ct] = __builtin_amdgcn_mfma_f32_16x16x32_bf16(atf, bx, acc2[ct], 0, 0, 0);
      }
    }
    // epilogue: h2 -> classifier partial dot
    {
      float bias = b2[f];
#pragma unroll
      for (int ct = 0; ct < 8; ++ct) {
#pragma unroll
        for (int e = 0; e < 4; ++e) {
          int c = ct * 16 + q * 4 + e;
          if (c < R_) {
            float h = dvr[ct][e] * acc2[ct][e] + bias;
            h = h > 0.f ? h : 0.2f * h;
            size_t j = (size_t)c * H_ + f;
            ps0 += h * Wc[j];
            ps1 += h * Wc[(size_t)(H_ * R_) + j];
          }
        }
      }
    }
    __syncthreads();   // XS consumed (and, after hf=1, everything done)
  }

  // ---- classifier reduction (reuse XS slot; all XS reads are behind the barrier) ----
#pragma unroll
  for (int off = 32; off; off >>= 1) {
    ps0 += __shfl_xor(ps0, off, 64);
    ps1 += __shfl_xor(ps1, off, 64);
  }
  float* red = (float*)(smem + XS_OFF);
  if (lane == 0) { red[w * 2] = ps0; red[w * 2 + 1] = ps1; }
  __syncthreads();
  if (tid == 0) {
    float s0 = 0.f, s1 = 0.f;
#pragma unroll
    for (int i = 0; i < 8; ++i) { s0 += red[i * 2]; s1 += red[i * 2 + 1]; }
    out[b * 2 + 0] = s0 + bc[0];
    out[b * 2 + 1] = s1 + bc[1];
  }
}

extern "C" void kernel_launch(void* const* d_in, const int* in_sizes, int n_in,
                              void* d_out, int out_size, void* d_ws, size_t ws_size,
                              hipStream_t stream) {
  const float* mM = (const float*)d_in[0];
  const float* nf = (const float*)d_in[1];
  const float* W1 = (const float*)d_in[2];
  const float* b1 = (const float*)d_in[3];
  const float* W2 = (const float*)d_in[4];
  const float* b2 = (const float*)d_in[5];
  const float* Wc = (const float*)d_in[6];
  const float* bc = (const float*)d_in[7];
  float* out = (float*)d_out;

  short* W1t = (short*)d_ws;            // 32768 bf16
  short* W2t = W1t + 32768;             // 65536 bf16

  wt_setup<<<384, 256, 0, stream>>>(W1, W2, W1t, W2t);

  hipFuncSetAttribute((const void*)gnn_fused,
                      hipFuncAttributeMaxDynamicSharedMemorySize, LDS_SIZE);
  gnn_fused<<<512, 512, LDS_SIZE, stream>>>(mM, nf, b1, b2, Wc, bc, W1t, W2t, out);
}